// Round 2
// baseline (184.180 us; speedup 1.0000x reference)
//
#include <hip/hip_runtime.h>

// ---------- small vector helpers ----------
struct V3 { float x, y, z; };

__device__ __forceinline__ V3 v3add(V3 a, V3 b){ return {a.x+b.x, a.y+b.y, a.z+b.z}; }
__device__ __forceinline__ V3 v3sub(V3 a, V3 b){ return {a.x-b.x, a.y-b.y, a.z-b.z}; }
__device__ __forceinline__ V3 v3scale(V3 a, float s){ return {a.x*s, a.y*s, a.z*s}; }
__device__ __forceinline__ V3 v3mul(V3 a, V3 b){ return {a.x*b.x, a.y*b.y, a.z*b.z}; }
__device__ __forceinline__ float dot3(V3 a, V3 b){ return fmaf(a.x,b.x, fmaf(a.y,b.y, a.z*b.z)); }
__device__ __forceinline__ V3 nrm3(V3 a){
    float s = rsqrtf(fmaxf(dot3(a,a), 1e-20f));
    return v3scale(a, s);
}

// ---------- packed-texture layout in d_ws (float4 texels) ----------
// spec mip l: resolution R=512>>l, 6*R*R texels, at OFFS[l]; diffuse (16x16x6) after.
#define OFF0 0
#define OFF1 1572864
#define OFF2 1966080
#define OFF3 2064384
#define OFF4 2088960
#define OFF5 2095104
#define DIFF_OFF 2096640
#define TOTAL_TEXELS 2098176
#define WS_BYTES_NEEDED (TOTAL_TEXELS * 16)

// ---------- cube face / uv (matches reference _cube_face_uv) ----------
__device__ __forceinline__ void cube_face_uv(V3 d, int& face, float& u, float& v){
    float ax = fabsf(d.x), ay = fabsf(d.y), az = fabsf(d.z);
    bool is_x = (ax >= ay) && (ax >= az);
    bool is_y = (!is_x) && (ay >= az);
    face = is_x ? (d.x >= 0.f ? 0 : 1)
                : (is_y ? (d.y >= 0.f ? 2 : 3)
                        : (d.z >= 0.f ? 4 : 5));
    float ma = fmaxf(is_x ? ax : (is_y ? ay : az), 1e-20f);
    float un = (face == 0) ? -d.z : (face == 1) ? d.z : (face == 5) ? -d.x : d.x;
    float vn = (face == 2) ?  d.z : (face == 3) ? -d.z : -d.y;
    float inv = 1.0f / ma;
    u = un * inv;
    v = vn * inv;
}

// ---------- bilinear helpers ----------
struct BilinCoord { int x0i, x1i, y0i, y1i; float fx, fy; };

__device__ __forceinline__ BilinCoord bilin_coord(float u, float v, int R){
    float Rf = (float)R;
    float tu = fmaf(fmaf(u, 0.5f, 0.5f), Rf, -0.5f);
    float tv = fmaf(fmaf(v, 0.5f, 0.5f), Rf, -0.5f);
    float x0 = floorf(tu), y0 = floorf(tv);
    BilinCoord c;
    c.fx = tu - x0; c.fy = tv - y0;
    c.x0i = min(max((int)x0,     0), R-1);
    c.x1i = min(max((int)x0 + 1, 0), R-1);
    c.y0i = min(max((int)y0,     0), R-1);
    c.y1i = min(max((int)y0 + 1, 0), R-1);
    return c;
}

// packed (float4 texels) bilinear cube sample
__device__ __forceinline__ V3 bilinear_cube4(const float4* __restrict__ tex, int R,
                                             int face, float u, float v){
    BilinCoord c = bilin_coord(u, v, R);
    const float4* base = tex + (size_t)face * R * R;
    const float4* r0 = base + (size_t)c.y0i * R;
    const float4* r1 = base + (size_t)c.y1i * R;
    float4 a = r0[c.x0i];
    float4 b = r0[c.x1i];
    float4 d = r1[c.x0i];
    float4 e = r1[c.x1i];
    float w00 = (1.f-c.fx)*(1.f-c.fy), w01 = c.fx*(1.f-c.fy);
    float w10 = (1.f-c.fx)*c.fy,       w11 = c.fx*c.fy;
    V3 out;
    out.x = a.x*w00 + b.x*w01 + d.x*w10 + e.x*w11;
    out.y = a.y*w00 + b.y*w01 + d.y*w10 + e.y*w11;
    out.z = a.z*w00 + b.z*w01 + d.z*w10 + e.z*w11;
    return out;
}

// unpacked (3-float texels) bilinear cube sample — fallback path
__device__ __forceinline__ V3 bilinear_cube3(const float* __restrict__ tex, int R,
                                             int face, float u, float v){
    BilinCoord c = bilin_coord(u, v, R);
    const float* base = tex + (size_t)face * R * R * 3;
    const float* r0 = base + (size_t)c.y0i * R * 3;
    const float* r1 = base + (size_t)c.y1i * R * 3;
    const float* p00 = r0 + 3*c.x0i;
    const float* p01 = r0 + 3*c.x1i;
    const float* p10 = r1 + 3*c.x0i;
    const float* p11 = r1 + 3*c.x1i;
    float a0 = p00[0], a1 = p00[1], a2 = p00[2];
    float b0 = p01[0], b1 = p01[1], b2 = p01[2];
    float d0 = p10[0], d1 = p10[1], d2 = p10[2];
    float e0 = p11[0], e1 = p11[1], e2 = p11[2];
    float w00 = (1.f-c.fx)*(1.f-c.fy), w01 = c.fx*(1.f-c.fy);
    float w10 = (1.f-c.fx)*c.fy,       w11 = c.fx*c.fy;
    V3 out;
    out.x = a0*w00 + b0*w01 + d0*w10 + e0*w11;
    out.y = a1*w00 + b1*w01 + d1*w10 + e1*w11;
    out.z = a2*w00 + b2*w01 + d2*w10 + e2*w11;
    return out;
}

// fg_lut 256x256x2 bilinear, clamped — texels loaded as float2 (dwordx2)
__device__ __forceinline__ void sample_fg(const float* __restrict__ lut,
                                          float u, float v, float& fa, float& fb){
    const int W = 256, H = 256;
    float tu = fmaf(u, (float)W, -0.5f);
    float tv = fmaf(v, (float)H, -0.5f);
    float x0 = floorf(tu), y0 = floorf(tv);
    float fx = tu - x0,    fy = tv - y0;
    int x0i = min(max((int)x0,     0), W-1);
    int x1i = min(max((int)x0 + 1, 0), W-1);
    int y0i = min(max((int)y0,     0), H-1);
    int y1i = min(max((int)y0 + 1, 0), H-1);
    const float2* l2 = (const float2*)lut;
    float2 a = l2[(size_t)y0i*W + x0i];
    float2 b = l2[(size_t)y0i*W + x1i];
    float2 d = l2[(size_t)y1i*W + x0i];
    float2 e = l2[(size_t)y1i*W + x1i];
    float w00 = (1.f-fx)*(1.f-fy), w01 = fx*(1.f-fy);
    float w10 = (1.f-fx)*fy,       w11 = fx*fy;
    fa = a.x*w00 + b.x*w01 + d.x*w10 + e.x*w11;
    fb = a.y*w00 + b.y*w01 + d.y*w10 + e.y*w11;
}

// ---------- linear -> srgb ----------
__device__ __forceinline__ float lin2srgb(float x){
    float xs = (x > 0.0031308f) ? x : 1.0f;
    float p  = __builtin_amdgcn_exp2f(__builtin_amdgcn_logf(xs) * (1.0f/2.4f));
    return (x > 0.0031308f) ? fmaf(1.055f, p, -0.055f) : 12.92f * x;
}

__device__ __forceinline__ float clamp01(float x){ return fminf(fmaxf(x, 0.f), 1.f); }

// ---------- pre-pass: pack 3-float texels into float4 texels in ws ----------
__global__ __launch_bounds__(256)
void pack_kernel(const float* __restrict__ s0, const float* __restrict__ s1,
                 const float* __restrict__ s2, const float* __restrict__ s3,
                 const float* __restrict__ s4, const float* __restrict__ s5,
                 const float* __restrict__ diffuse,
                 float4* __restrict__ ws)
{
    int t = blockIdx.x * blockDim.x + threadIdx.x;
    if (t >= TOTAL_TEXELS) return;
    const float* src; int local;
    if      (t >= DIFF_OFF) { src = diffuse; local = t - DIFF_OFF; }
    else if (t >= OFF5)     { src = s5;      local = t - OFF5; }
    else if (t >= OFF4)     { src = s4;      local = t - OFF4; }
    else if (t >= OFF3)     { src = s3;      local = t - OFF3; }
    else if (t >= OFF2)     { src = s2;      local = t - OFF2; }
    else if (t >= OFF1)     { src = s1;      local = t - OFF1; }
    else                    { src = s0;      local = t; }
    float a = src[3*local], b = src[3*local+1], c = src[3*local+2];
    ws[t] = make_float4(a, b, c, 0.f);
}

// ---------- shared shading core ----------
template <bool PACKED>
__device__ __forceinline__ void shade_pixel(
    int i,
    const float* __restrict__ gb_pos, const float* __restrict__ gb_normal,
    const float* __restrict__ basecolor, const float* __restrict__ metallic,
    const float* __restrict__ roughness, const float* __restrict__ view_pos,
    const float* __restrict__ diffuse, const float* __restrict__ fg_lut,
    const float* __restrict__ s0, const float* __restrict__ s1,
    const float* __restrict__ s2, const float* __restrict__ s3,
    const float* __restrict__ s4, const float* __restrict__ s5,
    const float4* __restrict__ ws,
    float* __restrict__ out)
{
    V3 pos = { gb_pos[3*i],    gb_pos[3*i+1],    gb_pos[3*i+2] };
    V3 nrm = { gb_normal[3*i], gb_normal[3*i+1], gb_normal[3*i+2] };
    V3 bc  = { basecolor[3*i], basecolor[3*i+1], basecolor[3*i+2] };
    float m = metallic[i];
    float r = roughness[i];
    V3 vp  = { view_pos[0], view_pos[1], view_pos[2] };

    V3 wo = nrm3(v3sub(vp, pos));
    float ndv_raw = dot3(wo, nrm);
    V3 refl = nrm3(v3sub(v3scale(nrm, 2.0f*ndv_raw), wo));

    float one_m = 1.0f - m;
    V3 diff_alb = v3scale(bc, one_m);
    V3 spec_alb = { fmaf(m, bc.x, 0.04f*one_m),
                    fmaf(m, bc.y, 0.04f*one_m),
                    fmaf(m, bc.z, 0.04f*one_m) };

    // mip level
    const float MIN_R = 0.08f, MAX_R = 0.5f;
    float lo = (fminf(fmaxf(r, MIN_R), MAX_R) - MIN_R) / (MAX_R - MIN_R) * 4.0f;
    float hi = (fminf(fmaxf(r, MAX_R), 1.0f) - MAX_R) / (1.0f - MAX_R) + 4.0f;
    float mip = (r < MAX_R) ? lo : hi;
    mip = fminf(fmaxf(mip, 0.0f), 5.0f);
    int l0 = min((int)mip, 5);
    float f = mip - (float)l0;
    int l1 = min(l0 + 1, 5);

    int dface; float du, dv;
    cube_face_uv(nrm, dface, du, dv);
    int sface; float su, sv;
    cube_face_uv(refl, sface, su, sv);
    float NdotV = fmaxf(ndv_raw, 0.0001f);

    V3 ambient, specA, specB;
    if (PACKED) {
        // offset-select for the two mip levels (cndmask chains, no branches)
        int offA = OFF0;
        offA = (l0 == 1) ? OFF1 : offA; offA = (l0 == 2) ? OFF2 : offA;
        offA = (l0 == 3) ? OFF3 : offA; offA = (l0 == 4) ? OFF4 : offA;
        offA = (l0 == 5) ? OFF5 : offA;
        int offB = OFF0;
        offB = (l1 == 1) ? OFF1 : offB; offB = (l1 == 2) ? OFF2 : offB;
        offB = (l1 == 3) ? OFF3 : offB; offB = (l1 == 4) ? OFF4 : offB;
        offB = (l1 == 5) ? OFF5 : offB;
        ambient = bilinear_cube4(ws + DIFF_OFF, 16, dface, du, dv);
        specA   = bilinear_cube4(ws + offA, 512 >> l0, sface, su, sv);
        specB   = bilinear_cube4(ws + offB, 512 >> l1, sface, su, sv);
    } else {
        const float* tA = s0;
        tA = (l0 == 1) ? s1 : tA; tA = (l0 == 2) ? s2 : tA;
        tA = (l0 == 3) ? s3 : tA; tA = (l0 == 4) ? s4 : tA; tA = (l0 == 5) ? s5 : tA;
        const float* tB = s0;
        tB = (l1 == 1) ? s1 : tB; tB = (l1 == 2) ? s2 : tB;
        tB = (l1 == 3) ? s3 : tB; tB = (l1 == 4) ? s4 : tB; tB = (l1 == 5) ? s5 : tB;
        ambient = bilinear_cube3(diffuse, 16, dface, du, dv);
        specA   = bilinear_cube3(tA, 512 >> l0, sface, su, sv);
        specB   = bilinear_cube3(tB, 512 >> l1, sface, su, sv);
    }

    float fa, fb;
    sample_fg(fg_lut, NdotV, r, fa, fb);

    V3 spec = { specA.x + (specB.x - specA.x) * f,
                specA.y + (specB.y - specA.y) * f,
                specA.z + (specB.z - specA.z) * f };
    V3 reflc = { fmaf(spec_alb.x, fa, fb),
                 fmaf(spec_alb.y, fa, fb),
                 fmaf(spec_alb.z, fa, fb) };
    V3 rgb = v3add(v3mul(spec, reflc), v3mul(ambient, diff_alb));

    out[3*i+0] = lin2srgb(clamp01(rgb.x));
    out[3*i+1] = lin2srgb(clamp01(rgb.y));
    out[3*i+2] = lin2srgb(clamp01(rgb.z));
}

template <bool PACKED>
__global__ __launch_bounds__(256)
void envlight_kernel(const float* __restrict__ gb_pos,
                     const float* __restrict__ gb_normal,
                     const float* __restrict__ basecolor,
                     const float* __restrict__ metallic,
                     const float* __restrict__ roughness,
                     const float* __restrict__ view_pos,
                     const float* __restrict__ diffuse,
                     const float* __restrict__ fg_lut,
                     const float* __restrict__ s0,
                     const float* __restrict__ s1,
                     const float* __restrict__ s2,
                     const float* __restrict__ s3,
                     const float* __restrict__ s4,
                     const float* __restrict__ s5,
                     const float4* __restrict__ ws,
                     float* __restrict__ out,
                     int n)
{
    int i = blockIdx.x * blockDim.x + threadIdx.x;
    if (i >= n) return;
    shade_pixel<PACKED>(i, gb_pos, gb_normal, basecolor, metallic, roughness,
                        view_pos, diffuse, fg_lut, s0, s1, s2, s3, s4, s5, ws, out);
}

extern "C" void kernel_launch(void* const* d_in, const int* in_sizes, int n_in,
                              void* d_out, int out_size, void* d_ws, size_t ws_size,
                              hipStream_t stream) {
    const float* gb_pos    = (const float*)d_in[0];
    const float* gb_normal = (const float*)d_in[1];
    const float* basecolor = (const float*)d_in[2];
    const float* metallic  = (const float*)d_in[3];
    const float* roughness = (const float*)d_in[4];
    const float* view_pos  = (const float*)d_in[5];
    const float* diffuse   = (const float*)d_in[6];
    const float* fg_lut    = (const float*)d_in[7];
    const float* s0        = (const float*)d_in[8];
    const float* s1        = (const float*)d_in[9];
    const float* s2        = (const float*)d_in[10];
    const float* s3        = (const float*)d_in[11];
    const float* s4        = (const float*)d_in[12];
    const float* s5        = (const float*)d_in[13];
    float* out = (float*)d_out;

    int n = in_sizes[0] / 3;
    int block = 256;
    int grid = (n + block - 1) / block;

    if (ws_size >= (size_t)WS_BYTES_NEEDED) {
        float4* ws = (float4*)d_ws;
        int pgrid = (TOTAL_TEXELS + block - 1) / block;
        pack_kernel<<<pgrid, block, 0, stream>>>(s0, s1, s2, s3, s4, s5, diffuse, ws);
        envlight_kernel<true><<<grid, block, 0, stream>>>(gb_pos, gb_normal, basecolor,
            metallic, roughness, view_pos, diffuse, fg_lut,
            s0, s1, s2, s3, s4, s5, ws, out, n);
    } else {
        envlight_kernel<false><<<grid, block, 0, stream>>>(gb_pos, gb_normal, basecolor,
            metallic, roughness, view_pos, diffuse, fg_lut,
            s0, s1, s2, s3, s4, s5, (const float4*)nullptr, out, n);
    }
}

// Round 3
// 172.917 us; speedup vs baseline: 1.0651x; 1.0651x over previous
//
#include <hip/hip_runtime.h>
#include <hip/hip_fp16.h>

// ---------- small vector helpers ----------
struct V3 { float x, y, z; };

__device__ __forceinline__ V3 v3add(V3 a, V3 b){ return {a.x+b.x, a.y+b.y, a.z+b.z}; }
__device__ __forceinline__ V3 v3sub(V3 a, V3 b){ return {a.x-b.x, a.y-b.y, a.z-b.z}; }
__device__ __forceinline__ V3 v3scale(V3 a, float s){ return {a.x*s, a.y*s, a.z*s}; }
__device__ __forceinline__ V3 v3mul(V3 a, V3 b){ return {a.x*b.x, a.y*b.y, a.z*b.z}; }
__device__ __forceinline__ float dot3(V3 a, V3 b){ return fmaf(a.x,b.x, fmaf(a.y,b.y, a.z*b.z)); }
__device__ __forceinline__ V3 nrm3(V3 a){
    float s = rsqrtf(fmaxf(dot3(a,a), 1e-20f));
    return v3scale(a, s);
}

// ---------- packed pair-block texture layout in d_ws ----------
// Block x of a row holds fp16 texels {x, min(x+1,R-1)} in 16 aligned bytes, so a
// bilinear row-pair is ONE dwordx4 load. Block count == texel count per level.
struct __align__(16) PairBlock { __half2 h01, h23, h45, h67; };
// h0,h1,h2 = texel A rgb ; h3,h4,h5 = texel B rgb ; h6,h7 pad

#define OFF0 0
#define OFF1 1572864
#define OFF2 1966080
#define OFF3 2064384
#define OFF4 2088960
#define OFF5 2095104
#define DIFF_OFF 2096640
#define TOTAL_BLOCKS 2098176
#define WS_BYTES_NEEDED (TOTAL_BLOCKS * 16)   // 33,570,816 B (same as R2 -> known to fit)

// ---------- cube face / uv (matches reference _cube_face_uv) ----------
__device__ __forceinline__ void cube_face_uv(V3 d, int& face, float& u, float& v){
    float ax = fabsf(d.x), ay = fabsf(d.y), az = fabsf(d.z);
    bool is_x = (ax >= ay) && (ax >= az);
    bool is_y = (!is_x) && (ay >= az);
    face = is_x ? (d.x >= 0.f ? 0 : 1)
                : (is_y ? (d.y >= 0.f ? 2 : 3)
                        : (d.z >= 0.f ? 4 : 5));
    float ma = fmaxf(is_x ? ax : (is_y ? ay : az), 1e-20f);
    float un = (face == 0) ? -d.z : (face == 1) ? d.z : (face == 5) ? -d.x : d.x;
    float vn = (face == 2) ?  d.z : (face == 3) ? -d.z : -d.y;
    float inv = 1.0f / ma;
    u = un * inv;
    v = vn * inv;
}

__device__ __forceinline__ void pair_extract(const PairBlock& pb, V3& lo, V3& hi){
    lo.x = __low2float(pb.h01);  lo.y = __high2float(pb.h01); lo.z = __low2float(pb.h23);
    hi.x = __high2float(pb.h23); hi.y = __low2float(pb.h45);  hi.z = __high2float(pb.h45);
}

// bilinear cube sample from pair-block fp16 texture: 2 scattered dwordx4 loads
__device__ __forceinline__ V3 bilinear_pairtex(const PairBlock* __restrict__ lvl, int R,
                                               int face, float u, float v){
    float Rf = (float)R;
    float tu = fmaf(fmaf(u, 0.5f, 0.5f), Rf, -0.5f);
    float tv = fmaf(fmaf(v, 0.5f, 0.5f), Rf, -0.5f);
    float x0f = floorf(tu), y0f = floorf(tv);
    float fx = tu - x0f,    fy = tv - y0f;
    int x0 = (int)x0f;                       // in [-1, R-1]
    fx = (x0 < 0) ? 0.f : fx;                // left-clamp: both corners = texel 0
    int xb  = min(max(x0, 0), R-1);          // block index (block R-1 duplicates last texel)
    int y0i = min(max((int)y0f,     0), R-1);
    int y1i = min(max((int)y0f + 1, 0), R-1);
    const PairBlock* fb = lvl + (size_t)face * R * R;
    PairBlock b0 = fb[(size_t)y0i * R + xb];
    PairBlock b1 = fb[(size_t)y1i * R + xb];
    V3 l0, h0, l1, h1;
    pair_extract(b0, l0, h0);
    pair_extract(b1, l1, h1);
    V3 r0 = { l0.x + (h0.x-l0.x)*fx, l0.y + (h0.y-l0.y)*fx, l0.z + (h0.z-l0.z)*fx };
    V3 r1 = { l1.x + (h1.x-l1.x)*fx, l1.y + (h1.y-l1.y)*fx, l1.z + (h1.z-l1.z)*fx };
    return { r0.x + (r1.x-r0.x)*fy, r0.y + (r1.y-r0.y)*fy, r0.z + (r1.z-r0.z)*fy };
}

// unpacked (3-float texels) bilinear cube sample — fallback path
__device__ __forceinline__ V3 bilinear_cube3(const float* __restrict__ tex, int R,
                                             int face, float u, float v){
    float Rf = (float)R;
    float tu = fmaf(fmaf(u, 0.5f, 0.5f), Rf, -0.5f);
    float tv = fmaf(fmaf(v, 0.5f, 0.5f), Rf, -0.5f);
    float x0 = floorf(tu), y0 = floorf(tv);
    float fx = tu - x0,    fy = tv - y0;
    int x0i = min(max((int)x0,     0), R-1);
    int x1i = min(max((int)x0 + 1, 0), R-1);
    int y0i = min(max((int)y0,     0), R-1);
    int y1i = min(max((int)y0 + 1, 0), R-1);
    const float* base = tex + (size_t)face * R * R * 3;
    const float* r0 = base + (size_t)y0i * R * 3;
    const float* r1 = base + (size_t)y1i * R * 3;
    float a0 = r0[3*x0i], a1 = r0[3*x0i+1], a2 = r0[3*x0i+2];
    float b0 = r0[3*x1i], b1 = r0[3*x1i+1], b2 = r0[3*x1i+2];
    float d0 = r1[3*x0i], d1 = r1[3*x0i+1], d2 = r1[3*x0i+2];
    float e0 = r1[3*x1i], e1 = r1[3*x1i+1], e2 = r1[3*x1i+2];
    float w00 = (1.f-fx)*(1.f-fy), w01 = fx*(1.f-fy);
    float w10 = (1.f-fx)*fy,       w11 = fx*fy;
    V3 out;
    out.x = a0*w00 + b0*w01 + d0*w10 + e0*w11;
    out.y = a1*w00 + b1*w01 + d1*w10 + e1*w11;
    out.z = a2*w00 + b2*w01 + d2*w10 + e2*w11;
    return out;
}

// fg_lut 256x256x2 bilinear, clamped — texels loaded as float2
__device__ __forceinline__ void sample_fg(const float* __restrict__ lut,
                                          float u, float v, float& fa, float& fb){
    const int W = 256, H = 256;
    float tu = fmaf(u, (float)W, -0.5f);
    float tv = fmaf(v, (float)H, -0.5f);
    float x0 = floorf(tu), y0 = floorf(tv);
    float fx = tu - x0,    fy = tv - y0;
    int x0i = min(max((int)x0,     0), W-1);
    int x1i = min(max((int)x0 + 1, 0), W-1);
    int y0i = min(max((int)y0,     0), H-1);
    int y1i = min(max((int)y0 + 1, 0), H-1);
    const float2* l2 = (const float2*)lut;
    float2 a = l2[(size_t)y0i*W + x0i];
    float2 b = l2[(size_t)y0i*W + x1i];
    float2 d = l2[(size_t)y1i*W + x0i];
    float2 e = l2[(size_t)y1i*W + x1i];
    float w00 = (1.f-fx)*(1.f-fy), w01 = fx*(1.f-fy);
    float w10 = (1.f-fx)*fy,       w11 = fx*fy;
    fa = a.x*w00 + b.x*w01 + d.x*w10 + e.x*w11;
    fb = a.y*w00 + b.y*w01 + d.y*w10 + e.y*w11;
}

// ---------- linear -> srgb ----------
__device__ __forceinline__ float lin2srgb(float x){
    float xs = (x > 0.0031308f) ? x : 1.0f;
    float p  = __builtin_amdgcn_exp2f(__builtin_amdgcn_logf(xs) * (1.0f/2.4f));
    return (x > 0.0031308f) ? fmaf(1.055f, p, -0.055f) : 12.92f * x;
}

__device__ __forceinline__ float clamp01(float x){ return fminf(fmaxf(x, 0.f), 1.f); }

// ---------- pre-pass: build fp16 pair-block pyramid in ws ----------
__global__ __launch_bounds__(256)
void pack_kernel(const float* __restrict__ s0, const float* __restrict__ s1,
                 const float* __restrict__ s2, const float* __restrict__ s3,
                 const float* __restrict__ s4, const float* __restrict__ s5,
                 const float* __restrict__ diffuse,
                 PairBlock* __restrict__ ws)
{
    int t = blockIdx.x * blockDim.x + threadIdx.x;
    if (t >= TOTAL_BLOCKS) return;
    const float* src; int local; int Rmask;
    if      (t >= DIFF_OFF) { src = diffuse; local = t - DIFF_OFF; Rmask = 15;  }
    else if (t >= OFF5)     { src = s5;      local = t - OFF5;     Rmask = 15;  }
    else if (t >= OFF4)     { src = s4;      local = t - OFF4;     Rmask = 31;  }
    else if (t >= OFF3)     { src = s3;      local = t - OFF3;     Rmask = 63;  }
    else if (t >= OFF2)     { src = s2;      local = t - OFF2;     Rmask = 127; }
    else if (t >= OFF1)     { src = s1;      local = t - OFF1;     Rmask = 255; }
    else                    { src = s0;      local = t;            Rmask = 511; }
    int nb = ((local & Rmask) == Rmask) ? local : local + 1;   // row-clamped neighbor
    float ar = src[3*local], ag = src[3*local+1], ab = src[3*local+2];
    float br = src[3*nb],    bg = src[3*nb+1],    bb = src[3*nb+2];
    PairBlock pb;
    pb.h01 = __floats2half2_rn(ar, ag);
    pb.h23 = __floats2half2_rn(ab, br);
    pb.h45 = __floats2half2_rn(bg, bb);
    pb.h67 = __floats2half2_rn(0.f, 0.f);
    ws[t] = pb;
}

// ---------- shared shading core ----------
template <bool PACKED>
__device__ __forceinline__ void shade_pixel(
    int i,
    const float* __restrict__ gb_pos, const float* __restrict__ gb_normal,
    const float* __restrict__ basecolor, const float* __restrict__ metallic,
    const float* __restrict__ roughness, const float* __restrict__ view_pos,
    const float* __restrict__ diffuse, const float* __restrict__ fg_lut,
    const float* __restrict__ s0, const float* __restrict__ s1,
    const float* __restrict__ s2, const float* __restrict__ s3,
    const float* __restrict__ s4, const float* __restrict__ s5,
    const PairBlock* __restrict__ ws,
    float* __restrict__ out)
{
    V3 pos = { gb_pos[3*i],    gb_pos[3*i+1],    gb_pos[3*i+2] };
    V3 nrm = { gb_normal[3*i], gb_normal[3*i+1], gb_normal[3*i+2] };
    V3 bc  = { basecolor[3*i], basecolor[3*i+1], basecolor[3*i+2] };
    float m = metallic[i];
    float r = roughness[i];
    V3 vp  = { view_pos[0], view_pos[1], view_pos[2] };

    V3 wo = nrm3(v3sub(vp, pos));
    float ndv_raw = dot3(wo, nrm);
    V3 refl = nrm3(v3sub(v3scale(nrm, 2.0f*ndv_raw), wo));

    float one_m = 1.0f - m;
    V3 diff_alb = v3scale(bc, one_m);
    V3 spec_alb = { fmaf(m, bc.x, 0.04f*one_m),
                    fmaf(m, bc.y, 0.04f*one_m),
                    fmaf(m, bc.z, 0.04f*one_m) };

    // mip level
    const float MIN_R = 0.08f, MAX_R = 0.5f;
    float lo = (fminf(fmaxf(r, MIN_R), MAX_R) - MIN_R) / (MAX_R - MIN_R) * 4.0f;
    float hi = (fminf(fmaxf(r, MAX_R), 1.0f) - MAX_R) / (1.0f - MAX_R) + 4.0f;
    float mip = (r < MAX_R) ? lo : hi;
    mip = fminf(fmaxf(mip, 0.0f), 5.0f);
    int l0 = min((int)mip, 5);
    float f = mip - (float)l0;
    int l1 = min(l0 + 1, 5);

    int dface; float du, dv;
    cube_face_uv(nrm, dface, du, dv);
    int sface; float su, sv;
    cube_face_uv(refl, sface, su, sv);
    float NdotV = fmaxf(ndv_raw, 0.0001f);

    V3 ambient, specA, specB;
    if (PACKED) {
        int offA = OFF0;
        offA = (l0 == 1) ? OFF1 : offA; offA = (l0 == 2) ? OFF2 : offA;
        offA = (l0 == 3) ? OFF3 : offA; offA = (l0 == 4) ? OFF4 : offA;
        offA = (l0 == 5) ? OFF5 : offA;
        int offB = OFF0;
        offB = (l1 == 1) ? OFF1 : offB; offB = (l1 == 2) ? OFF2 : offB;
        offB = (l1 == 3) ? OFF3 : offB; offB = (l1 == 4) ? OFF4 : offB;
        offB = (l1 == 5) ? OFF5 : offB;
        ambient = bilinear_pairtex(ws + DIFF_OFF, 16, dface, du, dv);
        specA   = bilinear_pairtex(ws + offA, 512 >> l0, sface, su, sv);
        specB   = bilinear_pairtex(ws + offB, 512 >> l1, sface, su, sv);
    } else {
        const float* tA = s0;
        tA = (l0 == 1) ? s1 : tA; tA = (l0 == 2) ? s2 : tA;
        tA = (l0 == 3) ? s3 : tA; tA = (l0 == 4) ? s4 : tA; tA = (l0 == 5) ? s5 : tA;
        const float* tB = s0;
        tB = (l1 == 1) ? s1 : tB; tB = (l1 == 2) ? s2 : tB;
        tB = (l1 == 3) ? s3 : tB; tB = (l1 == 4) ? s4 : tB; tB = (l1 == 5) ? s5 : tB;
        ambient = bilinear_cube3(diffuse, 16, dface, du, dv);
        specA   = bilinear_cube3(tA, 512 >> l0, sface, su, sv);
        specB   = bilinear_cube3(tB, 512 >> l1, sface, su, sv);
    }

    float fa, fb;
    sample_fg(fg_lut, NdotV, r, fa, fb);

    V3 spec = { specA.x + (specB.x - specA.x) * f,
                specA.y + (specB.y - specA.y) * f,
                specA.z + (specB.z - specA.z) * f };
    V3 reflc = { fmaf(spec_alb.x, fa, fb),
                 fmaf(spec_alb.y, fa, fb),
                 fmaf(spec_alb.z, fa, fb) };
    V3 rgb = v3add(v3mul(spec, reflc), v3mul(ambient, diff_alb));

    out[3*i+0] = lin2srgb(clamp01(rgb.x));
    out[3*i+1] = lin2srgb(clamp01(rgb.y));
    out[3*i+2] = lin2srgb(clamp01(rgb.z));
}

template <bool PACKED>
__global__ __launch_bounds__(256)
void envlight_kernel(const float* __restrict__ gb_pos,
                     const float* __restrict__ gb_normal,
                     const float* __restrict__ basecolor,
                     const float* __restrict__ metallic,
                     const float* __restrict__ roughness,
                     const float* __restrict__ view_pos,
                     const float* __restrict__ diffuse,
                     const float* __restrict__ fg_lut,
                     const float* __restrict__ s0,
                     const float* __restrict__ s1,
                     const float* __restrict__ s2,
                     const float* __restrict__ s3,
                     const float* __restrict__ s4,
                     const float* __restrict__ s5,
                     const PairBlock* __restrict__ ws,
                     float* __restrict__ out,
                     int n)
{
    int i = blockIdx.x * blockDim.x + threadIdx.x;
    if (i >= n) return;
    shade_pixel<PACKED>(i, gb_pos, gb_normal, basecolor, metallic, roughness,
                        view_pos, diffuse, fg_lut, s0, s1, s2, s3, s4, s5, ws, out);
}

extern "C" void kernel_launch(void* const* d_in, const int* in_sizes, int n_in,
                              void* d_out, int out_size, void* d_ws, size_t ws_size,
                              hipStream_t stream) {
    const float* gb_pos    = (const float*)d_in[0];
    const float* gb_normal = (const float*)d_in[1];
    const float* basecolor = (const float*)d_in[2];
    const float* metallic  = (const float*)d_in[3];
    const float* roughness = (const float*)d_in[4];
    const float* view_pos  = (const float*)d_in[5];
    const float* diffuse   = (const float*)d_in[6];
    const float* fg_lut    = (const float*)d_in[7];
    const float* s0        = (const float*)d_in[8];
    const float* s1        = (const float*)d_in[9];
    const float* s2        = (const float*)d_in[10];
    const float* s3        = (const float*)d_in[11];
    const float* s4        = (const float*)d_in[12];
    const float* s5        = (const float*)d_in[13];
    float* out = (float*)d_out;

    int n = in_sizes[0] / 3;
    int block = 256;
    int grid = (n + block - 1) / block;

    if (ws_size >= (size_t)WS_BYTES_NEEDED) {
        PairBlock* ws = (PairBlock*)d_ws;
        int pgrid = (TOTAL_BLOCKS + block - 1) / block;
        pack_kernel<<<pgrid, block, 0, stream>>>(s0, s1, s2, s3, s4, s5, diffuse, ws);
        envlight_kernel<true><<<grid, block, 0, stream>>>(gb_pos, gb_normal, basecolor,
            metallic, roughness, view_pos, diffuse, fg_lut,
            s0, s1, s2, s3, s4, s5, ws, out, n);
    } else {
        envlight_kernel<false><<<grid, block, 0, stream>>>(gb_pos, gb_normal, basecolor,
            metallic, roughness, view_pos, diffuse, fg_lut,
            s0, s1, s2, s3, s4, s5, (const PairBlock*)nullptr, out, n);
    }
}

// Round 4
// 167.604 us; speedup vs baseline: 1.0989x; 1.0317x over previous
//
#include <hip/hip_runtime.h>
#include <hip/hip_fp16.h>

// ---------- small vector helpers ----------
struct V3 { float x, y, z; };

__device__ __forceinline__ V3 v3add(V3 a, V3 b){ return {a.x+b.x, a.y+b.y, a.z+b.z}; }
__device__ __forceinline__ V3 v3sub(V3 a, V3 b){ return {a.x-b.x, a.y-b.y, a.z-b.z}; }
__device__ __forceinline__ V3 v3scale(V3 a, float s){ return {a.x*s, a.y*s, a.z*s}; }
__device__ __forceinline__ V3 v3mul(V3 a, V3 b){ return {a.x*b.x, a.y*b.y, a.z*b.z}; }
__device__ __forceinline__ float dot3(V3 a, V3 b){ return fmaf(a.x,b.x, fmaf(a.y,b.y, a.z*b.z)); }
__device__ __forceinline__ V3 nrm3(V3 a){
    float s = rsqrtf(fmaxf(dot3(a,a), 1e-20f));
    return v3scale(a, s);
}

// ---------- packed pair-block texture layout in d_ws ----------
// Spec/diffuse: fp16 pair-blocks {texel x, texel min(x+1,R-1)} in 16 aligned B.
// fg: f32 pair-blocks {lut[x].xy, lut[x+1].xy} in 16 B.
struct __align__(16) PairBlock { __half2 h01, h23, h45, h67; };

#define OFF0 0
#define OFF1 1572864
#define OFF2 1966080
#define OFF3 2064384
#define OFF4 2088960
#define OFF5 2095104
#define DIFF_OFF 2096640
#define FG_OFF 2098176
#define TOTAL_BLOCKS 2163712              // FG_OFF + 256*256
#define PACK_ONLY_BLOCKS 2098176          // R3-tier (no fg pairs)
#define WS_BYTES_FULL  ((size_t)TOTAL_BLOCKS * 16)      // 34,619,392 B
#define WS_BYTES_PACK  ((size_t)PACK_ONLY_BLOCKS * 16)  // 33,570,816 B (proven to fit)

// ---------- cube face / uv ----------
__device__ __forceinline__ void cube_face_uv(V3 d, int& face, float& u, float& v){
    float ax = fabsf(d.x), ay = fabsf(d.y), az = fabsf(d.z);
    bool is_x = (ax >= ay) && (ax >= az);
    bool is_y = (!is_x) && (ay >= az);
    face = is_x ? (d.x >= 0.f ? 0 : 1)
                : (is_y ? (d.y >= 0.f ? 2 : 3)
                        : (d.z >= 0.f ? 4 : 5));
    float ma = fmaxf(is_x ? ax : (is_y ? ay : az), 1e-20f);
    float un = (face == 0) ? -d.z : (face == 1) ? d.z : (face == 5) ? -d.x : d.x;
    float vn = (face == 2) ?  d.z : (face == 3) ? -d.z : -d.y;
    float inv = 1.0f / ma;
    u = un * inv;
    v = vn * inv;
}

__device__ __forceinline__ void pair_extract(const PairBlock& pb, V3& lo, V3& hi){
    lo.x = __low2float(pb.h01);  lo.y = __high2float(pb.h01); lo.z = __low2float(pb.h23);
    hi.x = __high2float(pb.h23); hi.y = __low2float(pb.h45);  hi.z = __high2float(pb.h45);
}

// bilinear from pair-block texture (works for global or LDS pointers)
__device__ __forceinline__ V3 bilinear_pairtex(const PairBlock* __restrict__ lvl, int R,
                                               int face, float u, float v){
    float Rf = (float)R;
    float tu = fmaf(fmaf(u, 0.5f, 0.5f), Rf, -0.5f);
    float tv = fmaf(fmaf(v, 0.5f, 0.5f), Rf, -0.5f);
    float x0f = floorf(tu), y0f = floorf(tv);
    float fx = tu - x0f,    fy = tv - y0f;
    int x0 = (int)x0f;
    fx = (x0 < 0) ? 0.f : fx;
    int xb  = min(max(x0, 0), R-1);
    int y0i = min(max((int)y0f,     0), R-1);
    int y1i = min(max((int)y0f + 1, 0), R-1);
    const PairBlock* fb = lvl + (size_t)face * R * R;
    PairBlock b0 = fb[(size_t)y0i * R + xb];
    PairBlock b1 = fb[(size_t)y1i * R + xb];
    V3 l0, h0, l1, h1;
    pair_extract(b0, l0, h0);
    pair_extract(b1, l1, h1);
    V3 r0 = { l0.x + (h0.x-l0.x)*fx, l0.y + (h0.y-l0.y)*fx, l0.z + (h0.z-l0.z)*fx };
    V3 r1 = { l1.x + (h1.x-l1.x)*fx, l1.y + (h1.y-l1.y)*fx, l1.z + (h1.z-l1.z)*fx };
    return { r0.x + (r1.x-r0.x)*fy, r0.y + (r1.y-r0.y)*fy, r0.z + (r1.z-r0.z)*fy };
}

// fg from f32 pair-blocks: 2 scattered dwordx4
__device__ __forceinline__ void sample_fg_pair(const float4* __restrict__ fgp,
                                               float u, float v, float& fa, float& fb){
    const int W = 256, H = 256;
    float tu = fmaf(u, (float)W, -0.5f);
    float tv = fmaf(v, (float)H, -0.5f);
    float x0f = floorf(tu), y0f = floorf(tv);
    float fx = tu - x0f,    fy = tv - y0f;
    int x0 = (int)x0f;
    fx = (x0 < 0) ? 0.f : fx;
    int xb  = min(max(x0, 0), W-1);
    int y0i = min(max((int)y0f,     0), H-1);
    int y1i = min(max((int)y0f + 1, 0), H-1);
    float4 r0 = fgp[(size_t)y0i * W + xb];   // {a.x,a.y,b.x,b.y}
    float4 r1 = fgp[(size_t)y1i * W + xb];
    float t0a = r0.x + (r0.z - r0.x)*fx, t0b = r0.y + (r0.w - r0.y)*fx;
    float t1a = r1.x + (r1.z - r1.x)*fx, t1b = r1.y + (r1.w - r1.y)*fx;
    fa = t0a + (t1a - t0a)*fy;
    fb = t0b + (t1b - t0b)*fy;
}

// fg from original float lut — MID-tier fallback
__device__ __forceinline__ void sample_fg(const float* __restrict__ lut,
                                          float u, float v, float& fa, float& fb){
    const int W = 256, H = 256;
    float tu = fmaf(u, (float)W, -0.5f);
    float tv = fmaf(v, (float)H, -0.5f);
    float x0 = floorf(tu), y0 = floorf(tv);
    float fx = tu - x0,    fy = tv - y0;
    int x0i = min(max((int)x0,     0), W-1);
    int x1i = min(max((int)x0 + 1, 0), W-1);
    int y0i = min(max((int)y0,     0), H-1);
    int y1i = min(max((int)y0 + 1, 0), H-1);
    const float2* l2 = (const float2*)lut;
    float2 a = l2[(size_t)y0i*W + x0i];
    float2 b = l2[(size_t)y0i*W + x1i];
    float2 d = l2[(size_t)y1i*W + x0i];
    float2 e = l2[(size_t)y1i*W + x1i];
    float w00 = (1.f-fx)*(1.f-fy), w01 = fx*(1.f-fy);
    float w10 = (1.f-fx)*fy,       w11 = fx*fy;
    fa = a.x*w00 + b.x*w01 + d.x*w10 + e.x*w11;
    fb = a.y*w00 + b.y*w01 + d.y*w10 + e.y*w11;
}

// unpacked bilinear — fallback tier
__device__ __forceinline__ V3 bilinear_cube3(const float* __restrict__ tex, int R,
                                             int face, float u, float v){
    float Rf = (float)R;
    float tu = fmaf(fmaf(u, 0.5f, 0.5f), Rf, -0.5f);
    float tv = fmaf(fmaf(v, 0.5f, 0.5f), Rf, -0.5f);
    float x0 = floorf(tu), y0 = floorf(tv);
    float fx = tu - x0,    fy = tv - y0;
    int x0i = min(max((int)x0,     0), R-1);
    int x1i = min(max((int)x0 + 1, 0), R-1);
    int y0i = min(max((int)y0,     0), R-1);
    int y1i = min(max((int)y0 + 1, 0), R-1);
    const float* base = tex + (size_t)face * R * R * 3;
    const float* r0 = base + (size_t)y0i * R * 3;
    const float* r1 = base + (size_t)y1i * R * 3;
    float a0 = r0[3*x0i], a1 = r0[3*x0i+1], a2 = r0[3*x0i+2];
    float b0 = r0[3*x1i], b1 = r0[3*x1i+1], b2 = r0[3*x1i+2];
    float d0 = r1[3*x0i], d1 = r1[3*x0i+1], d2 = r1[3*x0i+2];
    float e0 = r1[3*x1i], e1 = r1[3*x1i+1], e2 = r1[3*x1i+2];
    float w00 = (1.f-fx)*(1.f-fy), w01 = fx*(1.f-fy);
    float w10 = (1.f-fx)*fy,       w11 = fx*fy;
    V3 out;
    out.x = a0*w00 + b0*w01 + d0*w10 + e0*w11;
    out.y = a1*w00 + b1*w01 + d1*w10 + e1*w11;
    out.z = a2*w00 + b2*w01 + d2*w10 + e2*w11;
    return out;
}

// ---------- linear -> srgb ----------
__device__ __forceinline__ float lin2srgb(float x){
    float xs = (x > 0.0031308f) ? x : 1.0f;
    float p  = __builtin_amdgcn_exp2f(__builtin_amdgcn_logf(xs) * (1.0f/2.4f));
    return (x > 0.0031308f) ? fmaf(1.055f, p, -0.055f) : 12.92f * x;
}

__device__ __forceinline__ float clamp01(float x){ return fminf(fmaxf(x, 0.f), 1.f); }

// ---------- pre-pass ----------
__global__ __launch_bounds__(256)
void pack_kernel(const float* __restrict__ s0, const float* __restrict__ s1,
                 const float* __restrict__ s2, const float* __restrict__ s3,
                 const float* __restrict__ s4, const float* __restrict__ s5,
                 const float* __restrict__ diffuse, const float* __restrict__ fg_lut,
                 PairBlock* __restrict__ ws, int total)
{
    int t = blockIdx.x * blockDim.x + threadIdx.x;
    if (t >= total) return;
    if (t >= FG_OFF) {
        int local = t - FG_OFF;
        int x = local & 255;
        int nb = (x == 255) ? local : local + 1;
        float4 v = make_float4(fg_lut[2*local], fg_lut[2*local+1],
                               fg_lut[2*nb],    fg_lut[2*nb+1]);
        ((float4*)ws)[t] = v;
        return;
    }
    const float* src; int local; int Rmask;
    if      (t >= DIFF_OFF) { src = diffuse; local = t - DIFF_OFF; Rmask = 15;  }
    else if (t >= OFF5)     { src = s5;      local = t - OFF5;     Rmask = 15;  }
    else if (t >= OFF4)     { src = s4;      local = t - OFF4;     Rmask = 31;  }
    else if (t >= OFF3)     { src = s3;      local = t - OFF3;     Rmask = 63;  }
    else if (t >= OFF2)     { src = s2;      local = t - OFF2;     Rmask = 127; }
    else if (t >= OFF1)     { src = s1;      local = t - OFF1;     Rmask = 255; }
    else                    { src = s0;      local = t;            Rmask = 511; }
    int nb = ((local & Rmask) == Rmask) ? local : local + 1;
    float ar = src[3*local], ag = src[3*local+1], ab = src[3*local+2];
    float br = src[3*nb],    bg = src[3*nb+1],    bb = src[3*nb+2];
    PairBlock pb;
    pb.h01 = __floats2half2_rn(ar, ag);
    pb.h23 = __floats2half2_rn(ab, br);
    pb.h45 = __floats2half2_rn(bg, bb);
    pb.h67 = __floats2half2_rn(0.f, 0.f);
    ws[t] = pb;
}

// ---------- per-pixel precomputed state (phase A) ----------
struct PixPre {
    V3 diff_alb, spec_alb;
    int sface; float su, sv;
    int dface; float du, dv;
    int offA, RA, offB, RB; float f;
    float ndotv, rough;
};

__device__ __forceinline__ PixPre pre_pixel(
    int i,
    const float* __restrict__ gb_pos, const float* __restrict__ gb_normal,
    const float* __restrict__ basecolor, const float* __restrict__ metallic,
    const float* __restrict__ roughness, V3 vp)
{
    V3 pos = { gb_pos[3*i],    gb_pos[3*i+1],    gb_pos[3*i+2] };
    V3 nrm = { gb_normal[3*i], gb_normal[3*i+1], gb_normal[3*i+2] };
    V3 bc  = { basecolor[3*i], basecolor[3*i+1], basecolor[3*i+2] };
    float m = metallic[i];
    float r = roughness[i];

    V3 wo = nrm3(v3sub(vp, pos));
    float ndv_raw = dot3(wo, nrm);
    V3 refl = nrm3(v3sub(v3scale(nrm, 2.0f*ndv_raw), wo));

    PixPre p;
    float one_m = 1.0f - m;
    p.diff_alb = v3scale(bc, one_m);
    p.spec_alb = { fmaf(m, bc.x, 0.04f*one_m),
                   fmaf(m, bc.y, 0.04f*one_m),
                   fmaf(m, bc.z, 0.04f*one_m) };
    p.ndotv = fmaxf(ndv_raw, 0.0001f);
    p.rough = r;

    const float MIN_R = 0.08f, MAX_R = 0.5f;
    float lo = (fminf(fmaxf(r, MIN_R), MAX_R) - MIN_R) / (MAX_R - MIN_R) * 4.0f;
    float hi = (fminf(fmaxf(r, MAX_R), 1.0f) - MAX_R) / (1.0f - MAX_R) + 4.0f;
    float mip = (r < MAX_R) ? lo : hi;
    mip = fminf(fmaxf(mip, 0.0f), 5.0f);
    int l0 = min((int)mip, 5);
    p.f = mip - (float)l0;
    int l1 = min(l0 + 1, 5);

    int offA = OFF0;
    offA = (l0 == 1) ? OFF1 : offA; offA = (l0 == 2) ? OFF2 : offA;
    offA = (l0 == 3) ? OFF3 : offA; offA = (l0 == 4) ? OFF4 : offA;
    offA = (l0 == 5) ? OFF5 : offA;
    int offB = OFF0;
    offB = (l1 == 1) ? OFF1 : offB; offB = (l1 == 2) ? OFF2 : offB;
    offB = (l1 == 3) ? OFF3 : offB; offB = (l1 == 4) ? OFF4 : offB;
    offB = (l1 == 5) ? OFF5 : offB;
    p.offA = offA; p.RA = 512 >> l0;
    p.offB = offB; p.RB = 512 >> l1;

    cube_face_uv(nrm, p.dface, p.du, p.dv);
    cube_face_uv(refl, p.sface, p.su, p.sv);
    return p;
}

// phase B: sampling + blend + store
template <bool FGPAIR>
__device__ __forceinline__ void finish_pixel(
    int i, const PixPre& p,
    const PairBlock* __restrict__ ws, const PairBlock* __restrict__ lds_diff,
    const float* __restrict__ fg_lut, float* __restrict__ out)
{
    V3 specA = bilinear_pairtex(ws + p.offA, p.RA, p.sface, p.su, p.sv);
    V3 specB = bilinear_pairtex(ws + p.offB, p.RB, p.sface, p.su, p.sv);
    V3 ambient = bilinear_pairtex(lds_diff, 16, p.dface, p.du, p.dv);
    float fa, fb;
    if (FGPAIR) sample_fg_pair((const float4*)(ws + FG_OFF), p.ndotv, p.rough, fa, fb);
    else        sample_fg(fg_lut, p.ndotv, p.rough, fa, fb);

    V3 spec = { specA.x + (specB.x - specA.x) * p.f,
                specA.y + (specB.y - specA.y) * p.f,
                specA.z + (specB.z - specA.z) * p.f };
    V3 reflc = { fmaf(p.spec_alb.x, fa, fb),
                 fmaf(p.spec_alb.y, fa, fb),
                 fmaf(p.spec_alb.z, fa, fb) };
    V3 rgb = v3add(v3mul(spec, reflc), v3mul(ambient, p.diff_alb));

    out[3*i+0] = lin2srgb(clamp01(rgb.x));
    out[3*i+1] = lin2srgb(clamp01(rgb.y));
    out[3*i+2] = lin2srgb(clamp01(rgb.z));
}

// ---------- packed main kernel: 2 px/thread, diffuse in LDS ----------
template <bool FGPAIR>
__global__ __launch_bounds__(256)
void envlight_packed(const float* __restrict__ gb_pos,
                     const float* __restrict__ gb_normal,
                     const float* __restrict__ basecolor,
                     const float* __restrict__ metallic,
                     const float* __restrict__ roughness,
                     const float* __restrict__ view_pos,
                     const float* __restrict__ fg_lut,
                     const PairBlock* __restrict__ ws,
                     float* __restrict__ out,
                     int n, int half)
{
    __shared__ PairBlock lds_diff[1536];   // 24 KB
    for (int t = threadIdx.x; t < 1536; t += 256)
        lds_diff[t] = ws[DIFF_OFF + t];
    __syncthreads();

    int i = blockIdx.x * blockDim.x + threadIdx.x;
    if (i >= half) return;
    int j = i + half;

    V3 vp = { view_pos[0], view_pos[1], view_pos[2] };

    PixPre pa = pre_pixel(i, gb_pos, gb_normal, basecolor, metallic, roughness, vp);
    if (j < n) {
        PixPre pb = pre_pixel(j, gb_pos, gb_normal, basecolor, metallic, roughness, vp);
        finish_pixel<FGPAIR>(i, pa, ws, lds_diff, fg_lut, out);
        finish_pixel<FGPAIR>(j, pb, ws, lds_diff, fg_lut, out);
    } else {
        finish_pixel<FGPAIR>(i, pa, ws, lds_diff, fg_lut, out);
    }
}

// ---------- fallback: fully unpacked, 1 px/thread ----------
__global__ __launch_bounds__(256)
void envlight_fallback(const float* __restrict__ gb_pos,
                       const float* __restrict__ gb_normal,
                       const float* __restrict__ basecolor,
                       const float* __restrict__ metallic,
                       const float* __restrict__ roughness,
                       const float* __restrict__ view_pos,
                       const float* __restrict__ diffuse,
                       const float* __restrict__ fg_lut,
                       const float* __restrict__ s0, const float* __restrict__ s1,
                       const float* __restrict__ s2, const float* __restrict__ s3,
                       const float* __restrict__ s4, const float* __restrict__ s5,
                       float* __restrict__ out, int n)
{
    int i = blockIdx.x * blockDim.x + threadIdx.x;
    if (i >= n) return;
    V3 vp = { view_pos[0], view_pos[1], view_pos[2] };
    PixPre p = pre_pixel(i, gb_pos, gb_normal, basecolor, metallic, roughness, vp);
    // map offsets back to mip index
    int l0 = 0;
    l0 = (p.offA == OFF1) ? 1 : l0; l0 = (p.offA == OFF2) ? 2 : l0;
    l0 = (p.offA == OFF3) ? 3 : l0; l0 = (p.offA == OFF4) ? 4 : l0;
    l0 = (p.offA == OFF5) ? 5 : l0;
    int l1 = 0;
    l1 = (p.offB == OFF1) ? 1 : l1; l1 = (p.offB == OFF2) ? 2 : l1;
    l1 = (p.offB == OFF3) ? 3 : l1; l1 = (p.offB == OFF4) ? 4 : l1;
    l1 = (p.offB == OFF5) ? 5 : l1;
    const float* tA = s0;
    tA = (l0 == 1) ? s1 : tA; tA = (l0 == 2) ? s2 : tA;
    tA = (l0 == 3) ? s3 : tA; tA = (l0 == 4) ? s4 : tA; tA = (l0 == 5) ? s5 : tA;
    const float* tB = s0;
    tB = (l1 == 1) ? s1 : tB; tB = (l1 == 2) ? s2 : tB;
    tB = (l1 == 3) ? s3 : tB; tB = (l1 == 4) ? s4 : tB; tB = (l1 == 5) ? s5 : tB;
    V3 ambient = bilinear_cube3(diffuse, 16, p.dface, p.du, p.dv);
    V3 specA   = bilinear_cube3(tA, p.RA, p.sface, p.su, p.sv);
    V3 specB   = bilinear_cube3(tB, p.RB, p.sface, p.su, p.sv);
    float fa, fb;
    sample_fg(fg_lut, p.ndotv, p.rough, fa, fb);
    V3 spec = { specA.x + (specB.x - specA.x) * p.f,
                specA.y + (specB.y - specA.y) * p.f,
                specA.z + (specB.z - specA.z) * p.f };
    V3 reflc = { fmaf(p.spec_alb.x, fa, fb),
                 fmaf(p.spec_alb.y, fa, fb),
                 fmaf(p.spec_alb.z, fa, fb) };
    V3 rgb = v3add(v3mul(spec, reflc), v3mul(ambient, p.diff_alb));
    out[3*i+0] = lin2srgb(clamp01(rgb.x));
    out[3*i+1] = lin2srgb(clamp01(rgb.y));
    out[3*i+2] = lin2srgb(clamp01(rgb.z));
}

extern "C" void kernel_launch(void* const* d_in, const int* in_sizes, int n_in,
                              void* d_out, int out_size, void* d_ws, size_t ws_size,
                              hipStream_t stream) {
    const float* gb_pos    = (const float*)d_in[0];
    const float* gb_normal = (const float*)d_in[1];
    const float* basecolor = (const float*)d_in[2];
    const float* metallic  = (const float*)d_in[3];
    const float* roughness = (const float*)d_in[4];
    const float* view_pos  = (const float*)d_in[5];
    const float* diffuse   = (const float*)d_in[6];
    const float* fg_lut    = (const float*)d_in[7];
    const float* s0        = (const float*)d_in[8];
    const float* s1        = (const float*)d_in[9];
    const float* s2        = (const float*)d_in[10];
    const float* s3        = (const float*)d_in[11];
    const float* s4        = (const float*)d_in[12];
    const float* s5        = (const float*)d_in[13];
    float* out = (float*)d_out;

    int n = in_sizes[0] / 3;
    int block = 256;

    bool full = ws_size >= WS_BYTES_FULL;
    bool mid  = ws_size >= WS_BYTES_PACK;
    if (full || mid) {
        PairBlock* ws = (PairBlock*)d_ws;
        int total = full ? TOTAL_BLOCKS : PACK_ONLY_BLOCKS;
        int pgrid = (total + block - 1) / block;
        pack_kernel<<<pgrid, block, 0, stream>>>(s0, s1, s2, s3, s4, s5,
                                                 diffuse, fg_lut, ws, total);
        int half = (n + 1) / 2;
        int grid = (half + block - 1) / block;
        if (full)
            envlight_packed<true><<<grid, block, 0, stream>>>(gb_pos, gb_normal,
                basecolor, metallic, roughness, view_pos, fg_lut, ws, out, n, half);
        else
            envlight_packed<false><<<grid, block, 0, stream>>>(gb_pos, gb_normal,
                basecolor, metallic, roughness, view_pos, fg_lut, ws, out, n, half);
    } else {
        int grid = (n + block - 1) / block;
        envlight_fallback<<<grid, block, 0, stream>>>(gb_pos, gb_normal, basecolor,
            metallic, roughness, view_pos, diffuse, fg_lut,
            s0, s1, s2, s3, s4, s5, out, n);
    }
}